// Round 3
// baseline (2681.840 us; speedup 1.0000x reference)
//
#include <hip/hip_runtime.h>

typedef unsigned short u16;
typedef short short8 __attribute__((ext_vector_type(8)));
typedef float floatx4 __attribute__((ext_vector_type(4)));

__device__ __forceinline__ float b2f(u16 h) {
  union { unsigned int u; float f; } z;
  z.u = ((unsigned int)h) << 16;
  return z.f;
}
__device__ __forceinline__ u16 f2b(float f) {
  union { float f; unsigned int u; } z;
  z.f = f;
  unsigned int u = z.u;
  unsigned int r = (u + 0x7fffu + ((u >> 16) & 1u)) >> 16;
  return (u16)r;
}

// ---------------- softmax over the 3 lambda scalars (fp32) -> scale weights ---------
__global__ void softmax3_kernel(const float* __restrict__ lam, float* __restrict__ w) {
  if (threadIdx.x == 0) {
    float a = lam[0], b = lam[1], c = lam[2];
    float m = fmaxf(a, fmaxf(b, c));
    float ea = __expf(a - m), eb = __expf(b - m), ec = __expf(c - m);
    float s = ea + eb + ec;
    w[0] = ea / s; w[1] = eb / s; w[2] = ec / s;
  }
}

// ---------------- cast fp32 -> bf16, 8 elems/thread ---------------------------------
__global__ __launch_bounds__(256)
void cast_f32_bf16(const float* __restrict__ src, u16* __restrict__ dst) {
  const long i = ((long)blockIdx.x * 256 + threadIdx.x) * 8;
  float4 v0 = *(const float4*)(src + i);
  float4 v1 = *(const float4*)(src + i + 4);
  u16 r[8] __attribute__((aligned(16)));
  r[0] = f2b(v0.x); r[1] = f2b(v0.y); r[2] = f2b(v0.z); r[3] = f2b(v0.w);
  r[4] = f2b(v1.x); r[5] = f2b(v1.y); r[6] = f2b(v1.z); r[7] = f2b(v1.w);
  *(uint4*)(dst + i) = *(const uint4*)r;
}

// ---------------- transpose fp32 src (b,R,Cc) -> bf16 dst (b,Cc,R) ------------------
__global__ __launch_bounds__(256)
void transpose_f32(const float* __restrict__ src, u16* __restrict__ dst,
                   int R, int Cc, long sSrc, long sDst) {
  __shared__ u16 t[64][66];
  const int tid = threadIdx.x;
  const long r0 = (long)blockIdx.x << 6;
  const long c0 = (long)blockIdx.y << 6;
  const float* s = src + (long)blockIdx.z * sSrc;
  u16* d = dst + (long)blockIdx.z * sDst;
  const int rr = tid >> 2;
  const int cb = (tid & 3) << 2;  // 0,4,8,12
#pragma unroll
  for (int h = 0; h < 4; h++) {
    int cc = cb + h * 16;
    float4 v = *(const float4*)(s + (r0 + rr) * Cc + c0 + cc);
    t[rr][cc + 0] = f2b(v.x); t[rr][cc + 1] = f2b(v.y);
    t[rr][cc + 2] = f2b(v.z); t[rr][cc + 3] = f2b(v.w);
  }
  __syncthreads();
  const int cr = tid >> 2;
  const int nb0 = (tid & 3) << 3;
#pragma unroll
  for (int h = 0; h < 2; h++) {
    int rb = nb0 + h * 32;
    u16 res[8] __attribute__((aligned(16)));
#pragma unroll
    for (int j = 0; j < 8; j++) res[j] = t[rb + j][cr];
    *(uint4*)(d + (c0 + cr) * R + r0 + rb) = *(const uint4*)res;
  }
}

// ---------------- transpose bf16 src (b,R,Cc) -> bf16 dst (b,Cc,R) ------------------
__global__ __launch_bounds__(256)
void transpose_bf(const u16* __restrict__ src, u16* __restrict__ dst,
                  int R, int Cc, long sSrc, long sDst) {
  __shared__ u16 t[64][66];
  const int tid = threadIdx.x;
  const long r0 = (long)blockIdx.x << 6;
  const long c0 = (long)blockIdx.y << 6;
  const u16* s = src + (long)blockIdx.z * sSrc;
  u16* d = dst + (long)blockIdx.z * sDst;
  const int rr = tid >> 2;
  const int cb = (tid & 3) << 3;
#pragma unroll
  for (int h = 0; h < 2; h++) {
    int cc = cb + h * 32;
    uint4 v = *(const uint4*)(s + (r0 + rr) * Cc + c0 + cc);
    const u16* u = (const u16*)&v;
#pragma unroll
    for (int j = 0; j < 8; j++) t[rr][cc + j] = u[j];
  }
  __syncthreads();
  const int cr = tid >> 2;
#pragma unroll
  for (int h = 0; h < 2; h++) {
    int rb = cb + h * 32;
    u16 res[8] __attribute__((aligned(16)));
#pragma unroll
    for (int j = 0; j < 8; j++) res[j] = t[rb + j][cr];
    *(uint4*)(d + (c0 + cr) * R + r0 + rb) = *(const uint4*)res;
  }
}

// ---------------- separable avg-pool (fp32 in, bf16 out) per 48x48 plane ------------
template <int KP>
__global__ __launch_bounds__(256)
void pool_kernel(const float* __restrict__ v, u16* __restrict__ out) {
  __shared__ float p[2304];
  __shared__ float hs[2304];
  const long plane = blockIdx.x;
  const float* src = v + plane * 2304;
  const int tid = threadIdx.x;
  for (int idx = tid; idx < 576; idx += 256) {
    float4 raw = *(const float4*)(src + idx * 4);
    p[idx * 4 + 0] = raw.x; p[idx * 4 + 1] = raw.y;
    p[idx * 4 + 2] = raw.z; p[idx * 4 + 3] = raw.w;
  }
  __syncthreads();
  for (int idx = tid; idx < 2304; idx += 256) {
    int y = idx / 48, x = idx - y * 48;
    float s = 0.f;
#pragma unroll
    for (int d = -(KP / 2); d <= KP / 2; d++) {
      int xx = x + d;
      if (xx >= 0 && xx < 48) s += p[y * 48 + xx];
    }
    hs[idx] = s;
  }
  __syncthreads();
  u16* dst = out + plane * 2304;
  const float inv = 1.0f / (float)(KP * KP);
  for (int idx = tid; idx < 2304; idx += 256) {
    int y = idx / 48, x = idx - y * 48;
    float s = 0.f;
#pragma unroll
    for (int d = -(KP / 2); d <= KP / 2; d++) {
      int yy = y + d;
      if (yy >= 0 && yy < 48) s += hs[yy * 48 + x];
    }
    dst[idx] = f2b(s * inv);
  }
}

// ---------------- GEMM: C = alpha * A(row-major MxK) * B^T (B is NxK row-major) ------
// BIAS_MODE: 0 none, 1 per-n, 2 per-m (bias fp32). OUT_F32: fp32 out else bf16.
template <int BIAS_MODE, bool OUT_F32, bool BETA_ACC>
__global__ __launch_bounds__(256)
void gemm_nt(const u16* __restrict__ A, long sA, int lda,
             const u16* __restrict__ Bm, long sB, int ldb,
             void* __restrict__ Cv, long sC, int ldc,
             const float* __restrict__ bias,
             const float* __restrict__ alphap, float alphac, int K) {
  __shared__ __align__(16) u16 As[128][40];
  __shared__ __align__(16) u16 Bs[128][40];
  const int tid = threadIdx.x;
  const long m0 = (long)blockIdx.x * 128;
  const long n0 = (long)blockIdx.y * 128;
  const u16* Ab = A + (long)blockIdx.z * sA + m0 * lda;
  const u16* Bb = Bm + (long)blockIdx.z * sB + n0 * ldb;
  const int sm = tid >> 2;
  const int sk = (tid & 3) << 3;
  const int wave = tid >> 6;
  const int lane = tid & 63;
  const int wr = (wave >> 1) << 6;
  const int wc = (wave & 1) << 6;
  const int quad = lane >> 4;
  const int lr = lane & 15;
  floatx4 acc[4][4] = {};
  for (int k0 = 0; k0 < K; k0 += 32) {
    uint4 a0 = *(const uint4*)(Ab + (long)sm * lda + k0 + sk);
    uint4 a1 = *(const uint4*)(Ab + (long)(sm + 64) * lda + k0 + sk);
    uint4 b0 = *(const uint4*)(Bb + (long)sm * ldb + k0 + sk);
    uint4 b1 = *(const uint4*)(Bb + (long)(sm + 64) * ldb + k0 + sk);
    __syncthreads();
    *(uint4*)(&As[sm][sk]) = a0;
    *(uint4*)(&As[sm + 64][sk]) = a1;
    *(uint4*)(&Bs[sm][sk]) = b0;
    *(uint4*)(&Bs[sm + 64][sk]) = b1;
    __syncthreads();
    short8 af[4], bfr[4];
#pragma unroll
    for (int i = 0; i < 4; i++) af[i] = *(const short8*)(&As[wr + i * 16 + lr][quad << 3]);
#pragma unroll
    for (int j = 0; j < 4; j++) bfr[j] = *(const short8*)(&Bs[wc + j * 16 + lr][quad << 3]);
#pragma unroll
    for (int i = 0; i < 4; i++)
#pragma unroll
      for (int j = 0; j < 4; j++)
        acc[i][j] = __builtin_amdgcn_mfma_f32_16x16x32_bf16(af[i], bfr[j], acc[i][j], 0, 0, 0);
  }
  const float alpha = alphac * (alphap ? alphap[0] : 1.0f);
  const long cb = (long)blockIdx.z * sC;
#pragma unroll
  for (int i = 0; i < 4; i++) {
#pragma unroll
    for (int r = 0; r < 4; r++) {
      long m = m0 + wr + i * 16 + quad * 4 + r;
      float bm = (BIAS_MODE == 2) ? bias[m] : 0.0f;
#pragma unroll
      for (int j = 0; j < 4; j++) {
        long n = n0 + wc + j * 16 + lr;
        float v = alpha * acc[i][j][r];
        if (BIAS_MODE == 1) v += bias[n];
        if (BIAS_MODE == 2) v += bm;
        long off = cb + m * (long)ldc + n;
        if (OUT_F32) {
          float* Cf = (float*)Cv;
          if (BETA_ACC) v += Cf[off];
          Cf[off] = v;
        } else {
          ((u16*)Cv)[off] = f2b(v);
        }
      }
    }
  }
}

// ---------------- row softmax over L=512, one wave per row, bf16 out -----------------
__global__ __launch_bounds__(256)
void softmax_rows(const float* __restrict__ S, u16* __restrict__ P) {
  const long row = (long)blockIdx.x * 4 + (threadIdx.x >> 6);
  const int lane = threadIdx.x & 63;
  const float* sr = S + row * 512;
  float4 v0 = *(const float4*)(sr + lane * 4);
  float4 v1 = *(const float4*)(sr + 256 + lane * 4);
  float m = fmaxf(fmaxf(fmaxf(v0.x, v0.y), fmaxf(v0.z, v0.w)),
                  fmaxf(fmaxf(v1.x, v1.y), fmaxf(v1.z, v1.w)));
#pragma unroll
  for (int o = 32; o > 0; o >>= 1) m = fmaxf(m, __shfl_xor(m, o));
  float e0 = __expf(v0.x - m), e1 = __expf(v0.y - m), e2 = __expf(v0.z - m), e3 = __expf(v0.w - m);
  float e4 = __expf(v1.x - m), e5 = __expf(v1.y - m), e6 = __expf(v1.z - m), e7 = __expf(v1.w - m);
  float s = ((e0 + e1) + (e2 + e3)) + ((e4 + e5) + (e6 + e7));
#pragma unroll
  for (int o = 32; o > 0; o >>= 1) s += __shfl_xor(s, o);
  const float inv = 1.0f / s;
  union { u16 u[4]; uint2 v; } pk;
  u16* pr = P + row * 512;
  pk.u[0] = f2b(e0 * inv); pk.u[1] = f2b(e1 * inv); pk.u[2] = f2b(e2 * inv); pk.u[3] = f2b(e3 * inv);
  *(uint2*)(pr + lane * 4) = pk.v;
  pk.u[0] = f2b(e4 * inv); pk.u[1] = f2b(e5 * inv); pk.u[2] = f2b(e6 * inv); pk.u[3] = f2b(e7 * inv);
  *(uint2*)(pr + 256 + lane * 4) = pk.v;
}

// ---------------- epilogue: out(b,c,n) = v_feat(b,c,n) + agg(b,n,c) (all fp32) -------
__global__ __launch_bounds__(256)
void epilogue_kernel(const float* __restrict__ agg, const float* __restrict__ vfeat,
                     float* __restrict__ out) {
  __shared__ float t[64][65];
  const int tid = threadIdx.x;
  const long n0 = (long)blockIdx.x << 6;
  const long c0 = (long)blockIdx.y << 6;
  const long b = blockIdx.z;
  const float* a = agg + b * (2304L * 1024);
  const int nr = tid >> 2;
  const int cb4 = (tid & 3) << 4;
#pragma unroll
  for (int h = 0; h < 4; h++) {
    int cc = cb4 + h * 4;
    float4 v = *(const float4*)(a + (n0 + nr) * 1024 + c0 + cc);
    t[nr][cc + 0] = v.x; t[nr][cc + 1] = v.y; t[nr][cc + 2] = v.z; t[nr][cc + 3] = v.w;
  }
  __syncthreads();
  const int cr = tid >> 2;
  const int nbase = (tid & 3) << 3;
#pragma unroll
  for (int h = 0; h < 2; h++) {
    int nb = nbase + h * 32;
    long row = (b * 1024 + c0 + cr) * 2304 + n0 + nb;
    float4 vf0 = *(const float4*)(vfeat + row);
    float4 vf1 = *(const float4*)(vfeat + row + 4);
    float4 o0, o1;
    o0.x = t[nb + 0][cr] + vf0.x; o0.y = t[nb + 1][cr] + vf0.y;
    o0.z = t[nb + 2][cr] + vf0.z; o0.w = t[nb + 3][cr] + vf0.w;
    o1.x = t[nb + 4][cr] + vf1.x; o1.y = t[nb + 5][cr] + vf1.y;
    o1.z = t[nb + 6][cr] + vf1.z; o1.w = t[nb + 7][cr] + vf1.w;
    *(float4*)(out + row) = o0;
    *(float4*)(out + row + 4) = o1;
  }
}

extern "C" void kernel_launch(void* const* d_in, const int* in_sizes, int n_in,
                              void* d_out, int out_size, void* d_ws, size_t ws_size,
                              hipStream_t stream) {
  const float* v_feat = (const float*)d_in[0];
  const float* t_tok  = (const float*)d_in[1];
  const float* Wq  = (const float*)d_in[2];
  const float* bq  = (const float*)d_in[3];
  const float* Wk  = (const float*)d_in[4];
  const float* bk  = (const float*)d_in[5];
  const float* Wv  = (const float*)d_in[6];
  const float* bv  = (const float*)d_in[7];
  const float* lam = (const float*)d_in[8];

  // Workspace (NB=2 batch chunks): ~98.6 MB total.
  char* const wsb = (char*)d_ws;
  float* wts  = (float*)(wsb);
  u16* WqT    = (u16*)(wsb + 256);
  u16* WkT    = (u16*)(wsb + 2097408);
  u16* WvT    = (u16*)(wsb + 3670272);
  u16* tt16   = (u16*)(wsb + 5243136);    // (B*L, Ct) bf16, 12.6 MB
  u16* ktxt   = (u16*)(wsb + 17826048);   // (B, L, C) bf16, 16.8 MB
  u16* vtxtT  = (u16*)(wsb + 34603264);   // (B, C, L) bf16, 16.8 MB
  u16* poolc  = (u16*)(wsb + 51380480);   // (NB, C, N) bf16, 9.4 MB
  u16* vflatc = (u16*)(wsb + 60817664);   // (NB, N, C) bf16 (aliases Sc)
  float* Sc   = (float*)(wsb + 60817664); // (NB*N, L) fp32, 9.4 MB
  u16* qc     = (u16*)(wsb + 70254848);   // (NB, N, C) bf16 (aliases Pc)
  u16* Pc     = qc;                       // (NB*N, L) bf16
  float* aggc = (float*)(wsb + 79692032); // (NB, N, C) fp32, 18.9 MB
  // end: 98566400

  float* out0 = (float*)d_out;
  const long NC = 2304L * 1024;
  const long NL = 2304L * 512;
  const long CN = 1024L * 2304;

  softmax3_kernel<<<1, 64, 0, stream>>>(lam, wts);

  transpose_f32<<<dim3(16, 16, 1), 256, 0, stream>>>(Wq, WqT, 1024, 1024, 0, 0);
  transpose_f32<<<dim3(12, 16, 1), 256, 0, stream>>>(Wk, WkT, 768, 1024, 0, 0);
  transpose_f32<<<dim3(12, 16, 1), 256, 0, stream>>>(Wv, WvT, 768, 1024, 0, 0);
  cast_f32_bf16<<<3072, 256, 0, stream>>>(t_tok, tt16);  // 6291456 elems

  // k_txt = t_tok_flat @ Wk + bk : (8192,1024), K=768
  gemm_nt<1, false, false><<<dim3(64, 8, 1), 256, 0, stream>>>(
      tt16, 0, 768, WkT, 0, 768, ktxt, 0, 1024, bk, nullptr, 1.0f, 768);
  // v_txtT(b) = Wv^T @ t_tok(b)^T + bv (per-m) : (1024,512) per batch, K=768
  gemm_nt<2, false, false><<<dim3(8, 4, 16), 256, 0, stream>>>(
      WvT, 0, 768, tt16, 512L * 768, 768, vtxtT, 1024L * 512, 512, bv, nullptr, 1.0f, 768);

  for (int ch = 0; ch < 8; ch++) {
    const long bb = 2L * ch;
    const float* vf_ch = v_feat + bb * CN;
    for (int idx = 0; idx < 3; idx++) {
      if (idx == 0) {
        // (NB,C,N) fp32 -> (NB,N,C) bf16 directly from v_feat
        transpose_f32<<<dim3(16, 36, 2), 256, 0, stream>>>(
            vf_ch, vflatc, 1024, 2304, CN, NC);
      } else {
        if (idx == 1)
          pool_kernel<3><<<2048, 256, 0, stream>>>(vf_ch, poolc);
        else
          pool_kernel<5><<<2048, 256, 0, stream>>>(vf_ch, poolc);
        transpose_bf<<<dim3(16, 36, 2), 256, 0, stream>>>(
            poolc, vflatc, 1024, 2304, CN, NC);
      }
      // q = vflat @ Wq + bq
      gemm_nt<1, false, false><<<dim3(18, 8, 2), 256, 0, stream>>>(
          vflatc, NC, 1024, WqT, 0, 1024, qc, NC, 1024, bq, nullptr, 1.0f, 1024);
      // S = (q @ k_txt^T) / 32  (fp32)  [overwrites vflatc]
      gemm_nt<0, true, false><<<dim3(18, 4, 2), 256, 0, stream>>>(
          qc, NC, 1024, ktxt + bb * (512L * 1024), 512L * 1024, 1024,
          Sc, NL, 512, nullptr, nullptr, 0.03125f, 1024);
      // P = softmax(S) (bf16, overwrites q region)
      softmax_rows<<<1152, 256, 0, stream>>>(Sc, Pc);
      // agg (+)= w[idx] * P @ v_txt
      if (idx == 0) {
        gemm_nt<0, true, false><<<dim3(18, 8, 2), 256, 0, stream>>>(
            Pc, NL, 512, vtxtT + bb * (1024L * 512), 1024L * 512, 512,
            aggc, NC, 1024, nullptr, wts + 0, 1.0f, 512);
      } else {
        gemm_nt<0, true, true><<<dim3(18, 8, 2), 256, 0, stream>>>(
            Pc, NL, 512, vtxtT + bb * (1024L * 512), 1024L * 512, 512,
            aggc, NC, 1024, nullptr, wts + idx, 1.0f, 512);
      }
    }
    // out0 chunk = v_feat + agg^T  (fp32)
    epilogue_kernel<<<dim3(36, 16, 2), 256, 0, stream>>>(aggc, vf_ch, out0 + bb * CN);
  }

  // out1 = t_tok (raw fp32 copy)
  hipMemcpyAsync((void*)(out0 + 37748736L), (const void*)t_tok, 25165824L,
                 hipMemcpyDeviceToDevice, stream);
}